// Round 1
// baseline (230.669 us; speedup 1.0000x reference)
//
#include <hip/hip_runtime.h>

// NeuralNDCG fused kernel for MI355X (gfx950).
// B=128, N=256. Mask provably all-false (yt = ymax - y + ymin >= 0 != -1).
// One workgroup per batch; 1024 threads; each thread holds an 8x8 fp32 tile
// of the 256x256 Sinkhorn matrix in registers (64 VGPRs).
//   thread t: ti = t>>5 (row tile 0..31), tj = t&31 (col tile 0..31)
//   rows i = ti*8+a, cols j = tj*8+b
//   Row reduce: 32 threads sharing ti = one half-wave -> shfl_xor 1,2,4,8,16
//   Col reduce: intra-thread 8 rows + shfl_xor(32) (pairs ti=2w,2w+1 in wave w)
//               -> LDS part[16][256] -> 256-thread tree.

#define NN 256

__device__ inline float rcp_f(float x) { return __builtin_amdgcn_rcpf(x); }

__device__ inline float halfSum(float v) {
    v += __shfl_xor(v, 1);
    v += __shfl_xor(v, 2);
    v += __shfl_xor(v, 4);
    v += __shfl_xor(v, 8);
    v += __shfl_xor(v, 16);
    return v;
}
__device__ inline float halfMax(float v) {
    v = fmaxf(v, __shfl_xor(v, 1));
    v = fmaxf(v, __shfl_xor(v, 2));
    v = fmaxf(v, __shfl_xor(v, 4));
    v = fmaxf(v, __shfl_xor(v, 8));
    v = fmaxf(v, __shfl_xor(v, 16));
    return v;
}

__global__ void minmax_kernel(const int* __restrict__ yt, int n, int* __restrict__ wsi) {
    int t = threadIdx.x;
    int mn = 0x7fffffff;
    int mx = (int)0x80000000;
    for (int idx = t; idx < n; idx += 256) {
        int v = yt[idx];
        mn = min(mn, v);
        mx = max(mx, v);
    }
    for (int m = 32; m; m >>= 1) {
        mn = min(mn, __shfl_xor(mn, m));
        mx = max(mx, __shfl_xor(mx, m));
    }
    __shared__ int smn[4], smx[4];
    if ((t & 63) == 0) { smn[t >> 6] = mn; smx[t >> 6] = mx; }
    __syncthreads();
    if (t == 0) {
        for (int i = 1; i < 4; ++i) { mn = min(mn, smn[i]); mx = max(mx, smx[i]); }
        wsi[0] = mn;
        wsi[1] = mx;
    }
}

__global__ __launch_bounds__(1024) void ndcg_main(const float* __restrict__ yp,
                                                  const int* __restrict__ ytr,
                                                  const int* __restrict__ wsi,
                                                  float* __restrict__ wsf) {
    const int b = blockIdx.x;
    const int t = threadIdx.x;
    const int l = t & 63;
    const int w = t >> 6;
    const int ti = t >> 5;
    const int tj = t & 31;

    __shared__ float s[NN], Bm[NN], g[NN], disc[NN], Dpre[NN + 1];
    __shared__ float4 part4[16 * (NN / 4)];   // [wave][256] partial col sums, 16KB
    __shared__ float4 colinv4[NN / 4];
    __shared__ float numAcc;
    __shared__ int hist[64];

    const int ymin = wsi[0];
    const int ymax = wsi[1];

    int ytv = 0;
    if (t < 64) hist[t] = 0;
    if (t < NN) {
        s[t] = yp[b * NN + t];
        int yv = ytr[b * NN + t];
        ytv = ymax - yv + ymin;                 // relevancy flip (never -1 => mask all false)
        g[t] = exp2f((float)ytv) - 1.0f;        // powered relevancies
        disc[t] = 1.0f / log2f((float)t + 2.0f);
    }
    if (t == 0) numAcc = 0.0f;
    __syncthreads();

    if (t < NN) {
        float sv = s[t];
        float acc = 0.0f;
        for (int k = 0; k < NN; ++k) acc += fabsf(sv - s[k]);
        Bm[t] = acc;
        int bin = ytv - ymin;
        bin = min(max(bin, 0), 63);
        atomicAdd(&hist[bin], 1);
    }
    if (t == 0) {
        float run = 0.0f;
        for (int p = 0; p < NN; ++p) { Dpre[p] = run; run += disc[p]; }
        Dpre[NN] = run;
    }
    __syncthreads();

    // ---- build P0 = softmax_j( s_j * (255 - 2 i) - Bm_j ) into registers ----
    float m[8][8];
    {
        float sj[8], bm[8];
#pragma unroll
        for (int bb = 0; bb < 8; ++bb) {
            sj[bb] = s[tj * 8 + bb];
            bm[bb] = Bm[tj * 8 + bb];
        }
#pragma unroll
        for (int a = 0; a < 8; ++a) {
            float sc = 255.0f - 2.0f * (float)(ti * 8 + a);
#pragma unroll
            for (int bb = 0; bb < 8; ++bb) m[a][bb] = sj[bb] * sc - bm[bb];
        }
#pragma unroll
        for (int a = 0; a < 8; ++a) {
            float mx = m[a][0];
#pragma unroll
            for (int bb = 1; bb < 8; ++bb) mx = fmaxf(mx, m[a][bb]);
            mx = halfMax(mx);                    // row max over all 256 cols
            float z = 0.0f;
#pragma unroll
            for (int bb = 0; bb < 8; ++bb) {
                m[a][bb] = expf(m[a][bb] - mx);
                z += m[a][bb];
            }
            z = halfSum(z);                      // row sum over all 256 cols
            float rz = rcp_f(z);                 // z >= 1 (contains exp(0))
#pragma unroll
            for (int bb = 0; bb < 8; ++bb) m[a][bb] *= rz;
        }
    }

    // ---- 50 Sinkhorn iterations (col-normalize then row-normalize) ----
    float* partf = (float*)part4;
    for (int it = 0; it < 50; ++it) {
        // column partial sums (this wave's 16 rows)
        float p[8];
#pragma unroll
        for (int bb = 0; bb < 8; ++bb) {
            float acc = m[0][bb];
#pragma unroll
            for (int a = 1; a < 8; ++a) acc += m[a][bb];
            acc += __shfl_xor(acc, 32);          // combine ti=2w and ti=2w+1
            p[bb] = acc;
        }
        if (l < 32) part4[w * 64 + tj * 2]     = make_float4(p[0], p[1], p[2], p[3]);
        else        part4[w * 64 + tj * 2 + 1] = make_float4(p[4], p[5], p[6], p[7]);
        __syncthreads();
        if (t < NN) {
            float cs = 0.0f;
#pragma unroll
            for (int ww = 0; ww < 16; ++ww) cs += partf[ww * NN + t];
            ((float*)colinv4)[t] = rcp_f(fmaxf(cs, 1e-10f));
        }
        __syncthreads();
        float4 c0 = colinv4[tj * 2];
        float4 c1 = colinv4[tj * 2 + 1];
        float cv[8] = {c0.x, c0.y, c0.z, c0.w, c1.x, c1.y, c1.z, c1.w};
#pragma unroll
        for (int a = 0; a < 8; ++a)
#pragma unroll
            for (int bb = 0; bb < 8; ++bb) m[a][bb] *= cv[bb];
        // row normalize
#pragma unroll
        for (int a = 0; a < 8; ++a) {
            float acc = m[a][0];
#pragma unroll
            for (int bb = 1; bb < 8; ++bb) acc += m[a][bb];
            acc = halfSum(acc);
            float ri = rcp_f(fmaxf(acc, 1e-10f));
#pragma unroll
            for (int bb = 0; bb < 8; ++bb) m[a][bb] *= ri;
        }
    }

    // ---- epilogue: ndcg_b = sum_i disc_i * (sum_j m_ij g_j) / (idcg + 1e-10) ----
    {
        float gv[8];
#pragma unroll
        for (int bb = 0; bb < 8; ++bb) gv[bb] = g[tj * 8 + bb];
        float q[8];
#pragma unroll
        for (int a = 0; a < 8; ++a) {
            float acc = 0.0f;
#pragma unroll
            for (int bb = 0; bb < 8; ++bb) acc += m[a][bb] * gv[bb];
            q[a] = halfSum(acc);                 // ground_truth for row ti*8+a
        }
        if ((t & 31) == 0) {
            float partial = 0.0f;
#pragma unroll
            for (int a = 0; a < 8; ++a) partial += disc[ti * 8 + a] * q[a];
            atomicAdd(&numAcc, partial);
        }
    }
    __syncthreads();

    if (t == 0) {
        // idcg via value histogram (sorted-descending DCG; ties give equal gains)
        int R = ymax - ymin + 1;
        if (R > 64) R = 64;
        float idcg = 0.0f;
        int off = 0;
        for (int vb = R - 1; vb >= 0; --vb) {
            int c = hist[vb];
            float gain = exp2f((float)(vb + ymin)) - 1.0f;
            idcg += gain * (Dpre[off + c] - Dpre[off]);
            off += c;
        }
        float nd = (idcg != 0.0f) ? numAcc / (idcg + 1e-10f) : 0.0f;
        atomicAdd(&wsf[0], nd);
        if (idcg != 0.0f) atomicAdd(&wsf[1], 1.0f);
    }
}

__global__ void finalize_kernel(const float* __restrict__ wsf, float* __restrict__ out) {
    float sum = wsf[0];
    float cnt = wsf[1];
    out[0] = (cnt > 0.0f) ? -(sum / fmaxf(cnt, 1.0f)) : 0.0f;
}

extern "C" void kernel_launch(void* const* d_in, const int* in_sizes, int n_in,
                              void* d_out, int out_size, void* d_ws, size_t ws_size,
                              hipStream_t stream) {
    const float* y_pred = (const float*)d_in[0];
    const int* y_true = (const int*)d_in[1];
    const int total = in_sizes[0];
    const int B = total / NN;

    int* wsi = (int*)d_ws;                 // wsi[0]=ymin, wsi[1]=ymax
    float* wsf = (float*)d_ws + 2;         // wsf[0]=sum(ndcg), wsf[1]=count

    hipMemsetAsync(d_ws, 0, 16, stream);
    minmax_kernel<<<1, 256, 0, stream>>>(y_true, total, wsi);
    ndcg_main<<<B, 1024, 0, stream>>>(y_pred, y_true, wsi, wsf);
    finalize_kernel<<<1, 1, 0, stream>>>(wsf, (float*)d_out);
}

// Round 2
// 179.932 us; speedup vs baseline: 1.2820x; 1.2820x over previous
//
#include <hip/hip_runtime.h>

// NeuralNDCG fused kernels for MI355X (gfx950). B=128, N=256.
// Mask provably all-false (yt = ymax - y + ymin >= 0, never -1.0).
// ndcg_main: one workgroup per batch, 1024 threads, thread owns an 8x8 tile
// of the 256x256 Sinkhorn matrix in VGPRs.
//   ti = t>>5 (row tile), tj = t&31 (col tile); rows 8ti..+7, cols 8tj..+7.
//   Row reduce  : 32 consecutive lanes share ti -> DPP xor1/xor2/halfmirror/
//                 mirror + one ds_swizzle(xor16). 1 DS op instead of 5.
//   Col reduce  : 32 partial sets (one per row-tile) in LDS, rotated float4
//                 layout (conflict-free b128 writes); reduced by ALL 16 waves
//                 (quad of lanes per column, DPP quad-reduce).

#define NN 256

template<int C>
__device__ __forceinline__ float dppmov(float v) {
    return __int_as_float(__builtin_amdgcn_update_dpp(0, __float_as_int(v), C, 0xF, 0xF, true));
}
__device__ __forceinline__ float swz16(float v) {  // value from lane^16 (mod 32)
    return __int_as_float(__builtin_amdgcn_ds_swizzle(__float_as_int(v), 0x401F));
}
__device__ __forceinline__ float sum32(float v) {  // sum over 32-lane group
    v += dppmov<0xB1>(v);    // xor 1 (quad_perm 1,0,3,2)
    v += dppmov<0x4E>(v);    // xor 2 (quad_perm 2,3,0,1)
    v += dppmov<0x141>(v);   // row_half_mirror == xor 4 after quads uniform
    v += dppmov<0x140>(v);   // row_mirror == xor 8 after 8-groups uniform
    v += swz16(v);           // xor 16
    return v;
}
__device__ __forceinline__ float max32(float v) {
    v = fmaxf(v, dppmov<0xB1>(v));
    v = fmaxf(v, dppmov<0x4E>(v));
    v = fmaxf(v, dppmov<0x141>(v));
    v = fmaxf(v, dppmov<0x140>(v));
    v = fmaxf(v, swz16(v));
    return v;
}
__device__ __forceinline__ float sum4(float v) {   // sum over quad (t>>2 groups)
    v += dppmov<0xB1>(v);
    v += dppmov<0x4E>(v);
    return v;
}

__global__ void minmax_kernel(const int* __restrict__ yt, int n, int* __restrict__ wsi) {
    int t = blockIdx.x * blockDim.x + threadIdx.x;
    int mn = 0x7f7f7f7f, mx = (int)0x80808080;
    for (int i = t; i < n; i += gridDim.x * blockDim.x) {
        int v = yt[i];
        mn = min(mn, v);
        mx = max(mx, v);
    }
    for (int m = 32; m; m >>= 1) {
        mn = min(mn, __shfl_xor(mn, m));
        mx = max(mx, __shfl_xor(mx, m));
    }
    __shared__ int smn[4], smx[4];
    int w = threadIdx.x >> 6;
    if ((threadIdx.x & 63) == 0) { smn[w] = mn; smx[w] = mx; }
    __syncthreads();
    if (threadIdx.x == 0) {
        for (int i = 1; i < 4; ++i) { mn = min(mn, smn[i]); mx = max(mx, smx[i]); }
        atomicMin(&wsi[0], mn);
        atomicMax(&wsi[1], mx);
    }
}

__global__ __launch_bounds__(1024, 4) void ndcg_main(const float* __restrict__ yp,
                                                     const int* __restrict__ ytr,
                                                     const int* __restrict__ wsi,
                                                     float* __restrict__ wsf) {
    const int b = blockIdx.x;
    const int t = threadIdx.x;
    const int l = t & 63;
    const int ti = t >> 5;   // row tile 0..31 (== partial-set index)
    const int tj = t & 31;   // col tile 0..31

    __shared__ float4 part4[32 * 64];          // 32 KB: 32 sets x 256 cols (rotated)
    __shared__ float4 colinv4[64];             // 1 KB
    __shared__ __align__(16) float s[NN], Bm[NN], g[NN], disc[NN];
    __shared__ float numAcc, idcgAcc;
    __shared__ int hist[64];

    const int ymin = wsi[0];
    const int ymax = wsi[1];
    float* partf = (float*)part4;

    // ---- phase 1: load inputs ----
    int ytv = 0;
    if (t < 64) hist[t] = 0;
    if (t < NN) {
        s[t] = yp[b * NN + t];
        int yv = ytr[b * NN + t];
        ytv = ymax - yv + ymin;                // relevancy flip, mask all-false
        g[t] = exp2f((float)ytv) - 1.0f;       // powered relevancies
        disc[t] = 1.0f / log2f((float)t + 2.0f);
    }
    if (t == 0) { numAcc = 0.0f; idcgAcc = 0.0f; }
    __syncthreads();

    // ---- phase 2: Bm[j] = sum_k |s[j]-s[k]|, distributed over all 1024 ----
    {
        int j = t & 255, q = t >> 8;
        float sv = s[j];
        float acc = 0.0f;
        int k0 = q * 64;
#pragma unroll 8
        for (int k = 0; k < 64; ++k) acc += fabsf(sv - s[k0 + k]);
        partf[q * 256 + j] = acc;
    }
    __syncthreads();
    if (t < NN) {
        Bm[t] = partf[t] + partf[256 + t] + partf[512 + t] + partf[768 + t];
        int bin = min(max(ytv - ymin, 0), 63);
        atomicAdd(&hist[bin], 1);
    }
    __syncthreads();

    // ---- softmax rows: m[a][b] = exp(s_j*(255-2i) - Bm_j - rowmax)/rowsum ----
    float m[8][8];
    {
        float sj[8], bmj[8];
        ((float4*)sj)[0] = ((float4*)s)[tj * 2];
        ((float4*)sj)[1] = ((float4*)s)[tj * 2 + 1];
        ((float4*)bmj)[0] = ((float4*)Bm)[tj * 2];
        ((float4*)bmj)[1] = ((float4*)Bm)[tj * 2 + 1];
#pragma unroll
        for (int a = 0; a < 8; ++a) {
            float sc = (float)(255 - 2 * (ti * 8 + a));
#pragma unroll
            for (int bb = 0; bb < 8; ++bb) m[a][bb] = sj[bb] * sc - bmj[bb];
            float mx = fmaxf(fmaxf(fmaxf(m[a][0], m[a][1]), fmaxf(m[a][2], m[a][3])),
                             fmaxf(fmaxf(m[a][4], m[a][5]), fmaxf(m[a][6], m[a][7])));
            mx = max32(mx);
            float z = 0.0f;
#pragma unroll
            for (int bb = 0; bb < 8; ++bb) { m[a][bb] = expf(m[a][bb] - mx); z += m[a][bb]; }
            z = sum32(z);
            float rz = __builtin_amdgcn_rcpf(z);
#pragma unroll
            for (int bb = 0; bb < 8; ++bb) m[a][bb] *= rz;
        }
    }

    // ---- 50 Sinkhorn iterations ----
    const int wslot = ti * 64 + ((tj + ti) & 31);      // rotated, conflict-free
    const int csj = t >> 2, csq = t & 3;
    const int csc = csj >> 3, csd = csj & 7;
    const int civ_idx = ((csd & 4) ? 128 : 0) + 4 * csc + (csd & 3);

    for (int it = 0; it < 50; ++it) {
        // column partials over this thread's 8 rows (tree)
        float p[8];
#pragma unroll
        for (int bb = 0; bb < 8; ++bb)
            p[bb] = ((m[0][bb] + m[1][bb]) + (m[2][bb] + m[3][bb])) +
                    ((m[4][bb] + m[5][bb]) + (m[6][bb] + m[7][bb]));
        part4[wslot]      = make_float4(p[0], p[1], p[2], p[3]);
        part4[wslot + 32] = make_float4(p[4], p[5], p[6], p[7]);
        __syncthreads();

        // column sums: thread quad per column, each lane sums 8 of 32 sets
        {
            float cs = 0.0f;
#pragma unroll
            for (int k = 0; k < 8; ++k) {
                int ss = 4 * k + csq;
                int slotr = ss * 64 + ((csc + ss) & 31) + ((csd & 4) ? 32 : 0);
                cs += partf[slotr * 4 + (csd & 3)];
            }
            cs = sum4(cs);
            float civ = __builtin_amdgcn_rcpf(fmaxf(cs, 1e-10f));
            if (csq == 0) ((float*)colinv4)[civ_idx] = civ;
        }
        __syncthreads();

        float cv[8];
        ((float4*)cv)[0] = colinv4[tj];
        ((float4*)cv)[1] = colinv4[32 + tj];
        // fused col-scale + row-sum, then row normalize
#pragma unroll
        for (int a = 0; a < 8; ++a) {
            float racc = 0.0f;
#pragma unroll
            for (int bb = 0; bb < 8; ++bb) { m[a][bb] *= cv[bb]; racc += m[a][bb]; }
            racc = sum32(racc);
            float ri = __builtin_amdgcn_rcpf(fmaxf(racc, 1e-10f));
#pragma unroll
            for (int bb = 0; bb < 8; ++bb) m[a][bb] *= ri;
        }
    }

    // ---- epilogue: numerator = sum_i disc_i * sum_j m_ij g_j ----
    {
        float gv[8];
        ((float4*)gv)[0] = ((float4*)g)[tj * 2];
        ((float4*)gv)[1] = ((float4*)g)[tj * 2 + 1];
        float partial = 0.0f;
#pragma unroll
        for (int a = 0; a < 8; ++a) {
            float acc = 0.0f;
#pragma unroll
            for (int bb = 0; bb < 8; ++bb) acc += m[a][bb] * gv[bb];
            acc = sum32(acc);                  // all 32 lanes hold row total
            partial += disc[ti * 8 + a] * acc;
        }
        if ((l & 31) == 0) atomicAdd(&numAcc, partial);  // one lane per row-tile
    }

    // ---- idcg: distributed via histogram (sorted-descending DCG) ----
    __syncthreads();
    if (t < NN) {
        int p = t;
        float gain_p = 0.0f;
        int off = 0;
        for (int vb = 63; vb >= 0; --vb) {
            int c = hist[vb];
            if (p >= off && p < off + c) gain_p = exp2f((float)(vb + ymin)) - 1.0f;
            off += c;
        }
        float contrib = disc[p] * gain_p;
        contrib = sum32(contrib);
        contrib += __shfl_xor(contrib, 32);
        if (t == 0 || t == 64 || t == 128 || t == 192)
            atomicAdd(&idcgAcc, contrib * 0.0f + __shfl_xor(contrib, 0) * 0.0f + contrib);
    }
    __syncthreads();

    if (t == 0) {
        float idcg = idcgAcc;
        float nd = (idcg != 0.0f) ? numAcc / (idcg + 1e-10f) : 0.0f;
        atomicAdd(&wsf[0], nd);
        if (idcg != 0.0f) atomicAdd(&wsf[1], 1.0f);
    }
}

__global__ void finalize_kernel(const float* __restrict__ wsf, float* __restrict__ out) {
    if (threadIdx.x == 0) {
        float sum = wsf[0];
        float cnt = wsf[1];
        out[0] = (cnt > 0.0f) ? -(sum / fmaxf(cnt, 1.0f)) : 0.0f;
    }
}

extern "C" void kernel_launch(void* const* d_in, const int* in_sizes, int n_in,
                              void* d_out, int out_size, void* d_ws, size_t ws_size,
                              hipStream_t stream) {
    const float* y_pred = (const float*)d_in[0];
    const int* y_true = (const int*)d_in[1];
    const int total = in_sizes[0];
    const int B = total / NN;

    int* wsi = (int*)d_ws;                   // [0]=ymin, [1]=ymax
    float* wsf = (float*)((char*)d_ws + 8);  // [0]=sum(ndcg), [1]=count

    hipMemsetAsync(wsi, 0x7f, 4, stream);        // min init = 0x7f7f7f7f
    hipMemsetAsync(wsi + 1, 0x80, 4, stream);    // max init = 0x80808080 (negative)
    hipMemsetAsync(wsf, 0, 8, stream);
    minmax_kernel<<<128, 256, 0, stream>>>(y_true, total, wsi);
    ndcg_main<<<B, 1024, 0, stream>>>(y_pred, y_true, wsi, wsf);
    finalize_kernel<<<1, 64, 0, stream>>>(wsf, (float*)d_out);
}